// Round 4
// baseline (514.434 us; speedup 1.0000x reference)
//
#include <hip/hip_runtime.h>
#include <stdint.h>

#define N_NODES 50000
#define N_EDGES 400000
#define MPAD    50048   // 391 * 128
#define SCAN_B  49      // ceil(50000/1024)

typedef __bf16 bf16x8 __attribute__((ext_vector_type(8)));
typedef float  f32x4  __attribute__((ext_vector_type(4)));
typedef unsigned short ushort_t;
typedef unsigned int   uint_t;

// ---------- bf16 helpers (RNE) ----------
__device__ __forceinline__ ushort_t f2b(float f){
    uint_t x = __float_as_uint(f);
    x += 0x7FFFu + ((x >> 16) & 1u);
    return (ushort_t)(x >> 16);
}
__device__ __forceinline__ float b2f(ushort_t h){
    return __uint_as_float(((uint_t)h) << 16);
}

// ---------- bijective XCD-chunked swizzle (m204) ----------
__device__ __forceinline__ int xcd_swz(int orig, int nwg){
    int q = nwg >> 3, r = nwg & 7;
    int xcd = orig & 7, idx = orig >> 3;
    int base = (xcd < r) ? xcd * (q + 1) : r * (q + 1) + (xcd - r) * q;
    return base + idx;
}

// ---------- CSR build ----------
__global__ void zero_two(int* a, int* b, int n){
    int i = blockIdx.x * blockDim.x + threadIdx.x;
    if (i < n){ a[i] = 0; b[i] = 0; }
}

__global__ void hist_kernel(const int* __restrict__ dst, int* __restrict__ deg, int E){
    int i = blockIdx.x * blockDim.x + threadIdx.x;
    if (i < E) atomicAdd(&deg[dst[i]], 1);
}

__global__ __launch_bounds__(1024) void blk_scan_kernel(
        const int* __restrict__ deg, int* __restrict__ offs,
        int* __restrict__ bsum, int n){
    __shared__ int buf[1024];
    const int t = threadIdx.x, b = blockIdx.x;
    const int i = b * 1024 + t;
    int v = (i < n) ? deg[i] : 0;
    buf[t] = v; __syncthreads();
    for (int off = 1; off < 1024; off <<= 1){
        int x = (t >= off) ? buf[t - off] : 0;
        __syncthreads();
        buf[t] += x;
        __syncthreads();
    }
    if (i < n) offs[i] = buf[t] - v;
    if (t == 1023) bsum[b] = buf[1023];
}

__global__ void bsum_scan_kernel(int* __restrict__ bsum, int nb){
    int t = threadIdx.x;
    int orig = (t < nb) ? bsum[t] : 0;
    int v = orig;
    #pragma unroll
    for (int off = 1; off < 64; off <<= 1){
        int x = __shfl_up(v, off, 64);
        if (t >= off) v += x;
    }
    if (t < nb) bsum[t] = v - orig;
}

__global__ __launch_bounds__(1024) void add_off_kernel(
        int* __restrict__ offs, const int* __restrict__ bsum, int n){
    int i = blockIdx.x * 1024 + threadIdx.x;
    if (i < n) offs[i] += bsum[blockIdx.x];
    if (i == 0) offs[n] = N_EDGES;
}

__global__ void fill_kernel(const int* __restrict__ src, const int* __restrict__ dst,
                            const int* __restrict__ offs, int* __restrict__ cursor,
                            int* __restrict__ nbr, int E){
    int i = blockIdx.x * blockDim.x + threadIdx.x;
    if (i < E){
        int d = dst[i];
        int p = atomicAdd(&cursor[d], 1);
        nbr[offs[d] + p] = src[i];
    }
}

// ---------- weight transpose: W [K,N] fp32 -> Wt [N,K] bf16 ----------
__global__ void wtrans_kernel(const float* __restrict__ W, ushort_t* __restrict__ Wt,
                              int K, int N){
    int i = blockIdx.x * blockDim.x + threadIdx.x;   // i = n*K + k
    if (i < K * N){
        int n = i / K, k = i - n * K;
        Wt[i] = f2b(W[k * N + n]);
    }
}

// ---------- GEMM helpers ----------
__device__ __forceinline__ void load16(const void* g, void* l){
    __builtin_amdgcn_global_load_lds((const __attribute__((address_space(1))) void*)g,
                                     (__attribute__((address_space(3))) void*)l, 16, 0, 0);
}

// ---------- GEMM: 128x128 tile, BK=32, double-buffered (T3 minimal recipe) ----------
// LDS [128][32] bf16 per buffer (8 KB); row = 4 chunks of 16B. Chunk slot
// p = c ^ ((row>>1)&3) (source-side pre-swizzle, rule 21; ds_read applies the
// same XOR) -> 2-way bank aliasing = free (m136).
// Loop: stage(t+1) -> compute(t) -> barrier (drains vmcnt+lgkm). Stage latency
// hides under compute. One barrier per K-step.
__global__ __launch_bounds__(256, 4) void gemm128_bt(const ushort_t* __restrict__ A,
                                                     const ushort_t* __restrict__ Bt,
                                                     ushort_t* __restrict__ C,
                                                     int NBN, int N, int K){
    __shared__ ushort_t As[2][128 * 32];   // 2 x 8 KB
    __shared__ ushort_t Bs[2][128 * 32];   // 2 x 8 KB
    const int tid  = threadIdx.x, lane = tid & 63, wave = tid >> 6;
    const int wg = xcd_swz(blockIdx.x, gridDim.x);
    const int bm = wg / NBN, bn = wg - bm * NBN;
    const int fr = lane & 15;
    const int wm = (wave >> 1) * 64, wn = (wave & 1) * 64;
    f32x4 acc[4][4] = {};

    const ushort_t* Ab = A  + (size_t)(bm * 128) * K;
    const ushort_t* Bb = Bt + (size_t)(bn * 128) * K;

    // this thread's two staging slots
    const int s0 = tid, s1 = tid + 256;
    const int r0s = s0 >> 2, c0s = (s0 & 3) ^ ((r0s >> 1) & 3);
    const int r1s = s1 >> 2, c1s = (s1 & 3) ^ ((r1s >> 1) & 3);

    auto stage = [&](int kt, int pb){
        load16(Ab + (size_t)r0s * K + kt + c0s * 8, (char*)As[pb] + s0 * 16);
        load16(Ab + (size_t)r1s * K + kt + c1s * 8, (char*)As[pb] + s1 * 16);
        load16(Bb + (size_t)r0s * K + kt + c0s * 8, (char*)Bs[pb] + s0 * 16);
        load16(Bb + (size_t)r1s * K + kt + c1s * 8, (char*)Bs[pb] + s1 * 16);
    };

    stage(0, 0);
    __syncthreads();                       // drains vmcnt(0): tile 0 ready
    const int NT = K >> 5;                 // 16 K-steps
    for (int t = 0; t < NT; ++t){
        const int cur = t & 1;
        if (t + 1 < NT) stage((t + 1) << 5, cur ^ 1);
        __builtin_amdgcn_sched_barrier(0); // keep stage issue above compute
        bf16x8 af[4], bf[4];
        #pragma unroll
        for (int q = 0; q < 4; q++){
            int row = wm + q * 16 + fr;
            int cx  = (lane >> 4) ^ ((row >> 1) & 3);
            af[q] = *(const bf16x8*)(const void*)(&As[cur][row * 32 + cx * 8]);
        }
        #pragma unroll
        for (int q = 0; q < 4; q++){
            int row = wn + q * 16 + fr;
            int cx  = (lane >> 4) ^ ((row >> 1) & 3);
            bf[q] = *(const bf16x8*)(const void*)(&Bs[cur][row * 32 + cx * 8]);
        }
        #pragma unroll
        for (int tm = 0; tm < 4; tm++)
            #pragma unroll
            for (int tn = 0; tn < 4; tn++)
                acc[tm][tn] = __builtin_amdgcn_mfma_f32_16x16x32_bf16(
                                  af[tm], bf[tn], acc[tm][tn], 0, 0, 0);
        __syncthreads();                   // tile t+1 landed; buf reads done
    }
    // epilogue: C/D layout col=lane&15, row=(lane>>4)*4+reg  [m89-verified]
    const int r0 = (lane >> 4) * 4, c0 = lane & 15;
    #pragma unroll
    for (int tm = 0; tm < 4; tm++){
        #pragma unroll
        for (int tn = 0; tn < 4; tn++){
            int rbase = bm * 128 + wm + tm * 16 + r0;
            int cidx  = bn * 128 + wn + tn * 16 + c0;
            #pragma unroll
            for (int reg = 0; reg < 4; reg++)
                C[(size_t)(rbase + reg) * N + cidx] = f2b(acc[tm][tn][reg]);
        }
    }
}

// ---------- layer-0 GEMM: fp32 A (fused f2b), double-buffered, N fixed 512 ----------
__global__ __launch_bounds__(256, 3) void gemm128_a32(const float* __restrict__ A,
                                                      const ushort_t* __restrict__ Bt,
                                                      ushort_t* __restrict__ C,
                                                      int K){
    __shared__ ushort_t As[2][128 * 32];
    __shared__ ushort_t Bs[2][128 * 32];
    const int tid  = threadIdx.x, lane = tid & 63, wave = tid >> 6;
    const int wg = xcd_swz(blockIdx.x, gridDim.x);
    const int bm = wg >> 2, bn = wg & 3;          // NBN = 4 (N = 512)
    const int fr = lane & 15;
    const int wm = (wave >> 1) * 64, wn = (wave & 1) * 64;
    f32x4 acc[4][4] = {};

    const ushort_t* Bb = Bt + (size_t)(bn * 128) * K;
    const int s0 = tid, s1 = tid + 256;
    const int r0s = s0 >> 2, c0s = (s0 & 3) ^ ((r0s >> 1) & 3);
    const int r1s = s1 >> 2, c1s = (s1 & 3) ^ ((r1s >> 1) & 3);
    const int g0 = bm * 128 + r0s, g1 = bm * 128 + r1s;

    float4 x0, y0, x1, y1;                 // in-flight A payload (2 slots)
    auto loadA = [&](int kt){
        if (g0 < N_NODES){
            const float* p = A + (size_t)g0 * K + kt + c0s * 8;
            x0 = *(const float4*)(const void*)p;
            y0 = *(const float4*)(const void*)(p + 4);
        } else { x0 = make_float4(0,0,0,0); y0 = make_float4(0,0,0,0); }
        if (g1 < N_NODES){
            const float* p = A + (size_t)g1 * K + kt + c1s * 8;
            x1 = *(const float4*)(const void*)p;
            y1 = *(const float4*)(const void*)(p + 4);
        } else { x1 = make_float4(0,0,0,0); y1 = make_float4(0,0,0,0); }
    };
    auto stageB = [&](int kt, int pb){
        load16(Bb + (size_t)r0s * K + kt + c0s * 8, (char*)Bs[pb] + s0 * 16);
        load16(Bb + (size_t)r1s * K + kt + c1s * 8, (char*)Bs[pb] + s1 * 16);
    };
    auto writeA = [&](int pb){
        uint4 o;
        o.x = (uint_t)f2b(x0.x) | ((uint_t)f2b(x0.y) << 16);
        o.y = (uint_t)f2b(x0.z) | ((uint_t)f2b(x0.w) << 16);
        o.z = (uint_t)f2b(y0.x) | ((uint_t)f2b(y0.y) << 16);
        o.w = (uint_t)f2b(y0.z) | ((uint_t)f2b(y0.w) << 16);
        *(uint4*)(void*)((char*)As[pb] + s0 * 16) = o;
        o.x = (uint_t)f2b(x1.x) | ((uint_t)f2b(x1.y) << 16);
        o.y = (uint_t)f2b(x1.z) | ((uint_t)f2b(x1.w) << 16);
        o.z = (uint_t)f2b(y1.x) | ((uint_t)f2b(y1.y) << 16);
        o.w = (uint_t)f2b(y1.z) | ((uint_t)f2b(y1.w) << 16);
        *(uint4*)(void*)((char*)As[pb] + s1 * 16) = o;
    };

    // prologue: tile 0
    loadA(0); stageB(0, 0); writeA(0);
    __syncthreads();
    const int NT = K >> 5;
    for (int t = 0; t < NT; ++t){
        const int cur = t & 1;
        if (t + 1 < NT){ loadA((t + 1) << 5); stageB((t + 1) << 5, cur ^ 1); }
        __builtin_amdgcn_sched_barrier(0);
        bf16x8 af[4], bf[4];
        #pragma unroll
        for (int q = 0; q < 4; q++){
            int row = wm + q * 16 + fr;
            int cx  = (lane >> 4) ^ ((row >> 1) & 3);
            af[q] = *(const bf16x8*)(const void*)(&As[cur][row * 32 + cx * 8]);
        }
        #pragma unroll
        for (int q = 0; q < 4; q++){
            int row = wn + q * 16 + fr;
            int cx  = (lane >> 4) ^ ((row >> 1) & 3);
            bf[q] = *(const bf16x8*)(const void*)(&Bs[cur][row * 32 + cx * 8]);
        }
        #pragma unroll
        for (int tm = 0; tm < 4; tm++)
            #pragma unroll
            for (int tn = 0; tn < 4; tn++)
                acc[tm][tn] = __builtin_amdgcn_mfma_f32_16x16x32_bf16(
                                  af[tm], bf[tn], acc[tm][tn], 0, 0, 0);
        if (t + 1 < NT) writeA(cur ^ 1);   // waits on A regs; write other buffer
        __syncthreads();
    }
    const int r0 = (lane >> 4) * 4, c0 = lane & 15;
    #pragma unroll
    for (int tm = 0; tm < 4; tm++){
        #pragma unroll
        for (int tn = 0; tn < 4; tn++){
            int rbase = bm * 128 + wm + tm * 16 + r0;
            int cidx  = bn * 128 + wn + tn * 16 + c0;
            #pragma unroll
            for (int reg = 0; reg < 4; reg++)
                C[(size_t)(rbase + reg) * 512 + cidx] = f2b(acc[tm][tn][reg]);
        }
    }
}

// ---------- aggregation (round-0 form: wave-per-node, 16B/lane, 8-deep) ----------
__device__ __forceinline__ void acc8(float* a, uint4 y){
    a[0] += b2f((ushort_t)(y.x & 0xffff)); a[1] += b2f((ushort_t)(y.x >> 16));
    a[2] += b2f((ushort_t)(y.y & 0xffff)); a[3] += b2f((ushort_t)(y.y >> 16));
    a[4] += b2f((ushort_t)(y.z & 0xffff)); a[5] += b2f((ushort_t)(y.z >> 16));
    a[6] += b2f((ushort_t)(y.w & 0xffff)); a[7] += b2f((ushort_t)(y.w >> 16));
}
__device__ __forceinline__ void acc4(float* a, uint2 y){
    a[0] += b2f((ushort_t)(y.x & 0xffff)); a[1] += b2f((ushort_t)(y.x >> 16));
    a[2] += b2f((ushort_t)(y.y & 0xffff)); a[3] += b2f((ushort_t)(y.y >> 16));
}

// H[v] = relu((sum Y[nbr] + Y[v]) / (deg+1) + b), d=512, bf16 out
__global__ __launch_bounds__(256) void agg_relu_kernel(
        const ushort_t* __restrict__ Y, const int* __restrict__ offs,
        const int* __restrict__ nbr, const float* __restrict__ bias,
        ushort_t* __restrict__ H){
    const int lane = threadIdx.x & 63, wave = threadIdx.x >> 6;
    const int v = blockIdx.x * 4 + wave;
    const int off = lane * 8;
    float a[8];
    {   uint4 y = *(const uint4*)(const void*)(Y + (size_t)v * 512 + off);
        a[0] = b2f((ushort_t)(y.x & 0xffff)); a[1] = b2f((ushort_t)(y.x >> 16));
        a[2] = b2f((ushort_t)(y.y & 0xffff)); a[3] = b2f((ushort_t)(y.y >> 16));
        a[4] = b2f((ushort_t)(y.z & 0xffff)); a[5] = b2f((ushort_t)(y.z >> 16));
        a[6] = b2f((ushort_t)(y.w & 0xffff)); a[7] = b2f((ushort_t)(y.w >> 16)); }
    const int beg = offs[v], end = offs[v + 1];
    int i = beg;
    for (; i + 8 <= end; i += 8){
        uint4 yy[8];
        #pragma unroll
        for (int j = 0; j < 8; j++){
            int u = nbr[i + j];
            yy[j] = *(const uint4*)(const void*)(Y + (size_t)u * 512 + off);
        }
        #pragma unroll
        for (int j = 0; j < 8; j++) acc8(a, yy[j]);
    }
    for (; i + 4 <= end; i += 4){
        uint4 yy[4];
        #pragma unroll
        for (int j = 0; j < 4; j++){
            int u = nbr[i + j];
            yy[j] = *(const uint4*)(const void*)(Y + (size_t)u * 512 + off);
        }
        #pragma unroll
        for (int j = 0; j < 4; j++) acc8(a, yy[j]);
    }
    for (; i < end; i++){
        int u = nbr[i];
        uint4 y = *(const uint4*)(const void*)(Y + (size_t)u * 512 + off);
        acc8(a, y);
    }
    const float inv = 1.0f / (float)(end - beg + 1);
    float4 bb0 = ((const float4*)bias)[lane * 2];
    float4 bb1 = ((const float4*)bias)[lane * 2 + 1];
    float r[8];
    r[0] = a[0]*inv + bb0.x; r[1] = a[1]*inv + bb0.y;
    r[2] = a[2]*inv + bb0.z; r[3] = a[3]*inv + bb0.w;
    r[4] = a[4]*inv + bb1.x; r[5] = a[5]*inv + bb1.y;
    r[6] = a[6]*inv + bb1.z; r[7] = a[7]*inv + bb1.w;
    #pragma unroll
    for (int j = 0; j < 8; j++) r[j] = r[j] > 0.f ? r[j] : 0.f;
    uint4 o;
    o.x = (uint_t)f2b(r[0]) | ((uint_t)f2b(r[1]) << 16);
    o.y = (uint_t)f2b(r[2]) | ((uint_t)f2b(r[3]) << 16);
    o.z = (uint_t)f2b(r[4]) | ((uint_t)f2b(r[5]) << 16);
    o.w = (uint_t)f2b(r[6]) | ((uint_t)f2b(r[7]) << 16);
    *(uint4*)(void*)(H + (size_t)v * 512 + off) = o;
}

// final layer: d=256, fp32 out, no relu. wave per node, lane covers 4 elems
__global__ __launch_bounds__(256) void agg_out_kernel(
        const ushort_t* __restrict__ Y, const int* __restrict__ offs,
        const int* __restrict__ nbr, const float* __restrict__ bias,
        float* __restrict__ out){
    const int lane = threadIdx.x & 63, wave = threadIdx.x >> 6;
    const int v = blockIdx.x * 4 + wave;
    const int off = lane * 4;
    float a[4];
    {   uint2 y = *(const uint2*)(const void*)(Y + (size_t)v * 256 + off);
        a[0] = b2f((ushort_t)(y.x & 0xffff)); a[1] = b2f((ushort_t)(y.x >> 16));
        a[2] = b2f((ushort_t)(y.y & 0xffff)); a[3] = b2f((ushort_t)(y.y >> 16)); }
    const int beg = offs[v], end = offs[v + 1];
    int i = beg;
    for (; i + 8 <= end; i += 8){
        uint2 yy[8];
        #pragma unroll
        for (int j = 0; j < 8; j++){
            int u = nbr[i + j];
            yy[j] = *(const uint2*)(const void*)(Y + (size_t)u * 256 + off);
        }
        #pragma unroll
        for (int j = 0; j < 8; j++) acc4(a, yy[j]);
    }
    for (; i + 4 <= end; i += 4){
        uint2 yy[4];
        #pragma unroll
        for (int j = 0; j < 4; j++){
            int u = nbr[i + j];
            yy[j] = *(const uint2*)(const void*)(Y + (size_t)u * 256 + off);
        }
        #pragma unroll
        for (int j = 0; j < 4; j++) acc4(a, yy[j]);
    }
    for (; i < end; i++){
        int u = nbr[i];
        uint2 y = *(const uint2*)(const void*)(Y + (size_t)u * 256 + off);
        acc4(a, y);
    }
    const float inv = 1.0f / (float)(end - beg + 1);
    float4 bb = ((const float4*)bias)[lane];
    float4 r;
    r.x = a[0]*inv + bb.x; r.y = a[1]*inv + bb.y;
    r.z = a[2]*inv + bb.z; r.w = a[3]*inv + bb.w;
    ((float4*)out)[v * 64 + lane] = r;
}

extern "C" void kernel_launch(void* const* d_in, const int* in_sizes, int n_in,
                              void* d_out, int out_size, void* d_ws, size_t ws_size,
                              hipStream_t stream) {
    const float* feats = (const float*)d_in[0];
    const int*   src   = (const int*)  d_in[1];
    const int*   dst   = (const int*)  d_in[2];
    const float* W0    = (const float*)d_in[3];
    const float* b0    = (const float*)d_in[4];
    const float* W1    = (const float*)d_in[5];
    const float* b1    = (const float*)d_in[6];
    const float* W2    = (const float*)d_in[7];
    const float* b2    = (const float*)d_in[8];
    float* out = (float*)d_out;

    char* w = (char*)d_ws;
    ushort_t* Abuf = (ushort_t*)w;  w += (size_t)MPAD * 512 * 2;   // 51.25 MB (H buffer)
    ushort_t* Ybuf = (ushort_t*)w;  w += (size_t)MPAD * 512 * 2;   // 51.25 MB
    ushort_t* W0t  = (ushort_t*)w;  w += 512 * 512 * 2;
    ushort_t* W1t  = (ushort_t*)w;  w += 512 * 512 * 2;
    ushort_t* W2t  = (ushort_t*)w;  w += 256 * 512 * 2;
    int* deg    = (int*)w;          w += 50048 * 4;
    int* offs   = (int*)w;          w += 50056 * 4;
    int* cursor = (int*)w;          w += 50048 * 4;
    int* nbr    = (int*)w;          w += (size_t)N_EDGES * 4;
    int* bsum   = (int*)w;          w += 64 * 4;

    // CSR build
    zero_two<<<(N_NODES + 255) / 256, 256, 0, stream>>>(deg, cursor, N_NODES);
    hist_kernel<<<(N_EDGES + 255) / 256, 256, 0, stream>>>(dst, deg, N_EDGES);
    blk_scan_kernel<<<SCAN_B, 1024, 0, stream>>>(deg, offs, bsum, N_NODES);
    bsum_scan_kernel<<<1, 64, 0, stream>>>(bsum, SCAN_B);
    add_off_kernel<<<SCAN_B, 1024, 0, stream>>>(offs, bsum, N_NODES);
    fill_kernel<<<(N_EDGES + 255) / 256, 256, 0, stream>>>(src, dst, offs, cursor, nbr, N_EDGES);

    // weight transposes (f2b of feats is fused into gemm128_a32)
    wtrans_kernel<<<(512 * 512 + 255) / 256, 256, 0, stream>>>(W0, W0t, 512, 512);
    wtrans_kernel<<<(512 * 512 + 255) / 256, 256, 0, stream>>>(W1, W1t, 512, 512);
    wtrans_kernel<<<(512 * 256 + 255) / 256, 256, 0, stream>>>(W2, W2t, 512, 256);

    const int g01 = (MPAD / 128) * 4;   // 1564 blocks, bn-fastest
    const int g2  = (MPAD / 128) * 2;   // 782 blocks

    // layer 0: Y = feats @ W0t^T (fp32 A staged in-kernel); H = relu(agg(Y)+b0)
    gemm128_a32<<<g01, 256, 0, stream>>>(feats, W0t, Ybuf, 512);
    agg_relu_kernel<<<N_NODES / 4, 256, 0, stream>>>(Ybuf, offs, nbr, b0, Abuf);
    // layer 1
    gemm128_bt<<<g01, 256, 0, stream>>>(Abuf, W1t, Ybuf, 4, 512, 512);
    agg_relu_kernel<<<N_NODES / 4, 256, 0, stream>>>(Ybuf, offs, nbr, b1, Abuf);
    // layer 2 (no relu, fp32 out)
    gemm128_bt<<<g2, 256, 0, stream>>>(Abuf, W2t, Ybuf, 2, 256, 512);
    agg_out_kernel<<<N_NODES / 4, 256, 0, stream>>>(Ybuf, offs, nbr, b2, out);
}